// Round 1
// 10992.126 us; speedup vs baseline: 2.4858x; 2.4858x over previous
//
#include <hip/hip_runtime.h>

// 4-layer LSTM decoder. B=64, T=64, H=1024, V=32000, E=512.
// Round 2: recurrence moved to fp16 MFMA with pre-swizzled fragment-order weights.
// Per (t,layer) step: grid 64 blocks x 256 thr, no LDS, no barriers; B-frags stream
// linearly from L2/L3, A-frags read from fp16 h buffers. Cell update fused in epilogue.
// d_in: 0 idx[B][T] int32; 1..8 h1,c1..h4,c4 [64][1024] f32; 9 emb [V][E];
//       10+3l W,U,b per layer; 22 Wfc [1024][32000]; 23 bfc [32000].

#define B_ 64
#define T_ 64
#define H_ 1024
#define V_ 32000
#define E_ 512

typedef _Float16 v8h __attribute__((ext_vector_type(8)));
typedef float v4f __attribute__((ext_vector_type(4)));

// ---------------- gather: X16[t][b][e] = fp16(emb[idx[b][t]][e]) ----------------
__global__ __launch_bounds__(256) void gather_embed16(const int* __restrict__ idx,
                                                      const float* __restrict__ emb,
                                                      _Float16* __restrict__ X16) {
    int g = blockIdx.x * 256 + threadIdx.x;  // 8-elem chunk id; 262144 total (grid 1024)
    int row = g >> 6, off = g & 63;          // row = t*64+b, 64 chunks per 512-row
    int t = row >> 6, b = row & 63;
    int v = idx[b * T_ + t];
    const float4* s = (const float4*)(emb + (size_t)v * E_) + off * 2;
    float4 a = s[0], c = s[1];
    union { uint4 u; _Float16 h[8]; } o;
    o.h[0] = (_Float16)a.x; o.h[1] = (_Float16)a.y; o.h[2] = (_Float16)a.z; o.h[3] = (_Float16)a.w;
    o.h[4] = (_Float16)c.x; o.h[5] = (_Float16)c.y; o.h[6] = (_Float16)c.z; o.h[7] = (_Float16)c.w;
    ((uint4*)X16)[g] = o.u;
}

// ---------------- init state: h -> fp16 (parity 0 slots), c -> fp32 copy --------
__global__ __launch_bounds__(256) void init_state16(const float* h1, const float* c1,
                                                    const float* h2, const float* c2,
                                                    const float* h3, const float* c3,
                                                    const float* h4, const float* c4,
                                                    _Float16* __restrict__ h16,
                                                    _Float16* __restrict__ h4a,
                                                    float* __restrict__ cbuf) {
    int y = blockIdx.y;                      // 0..7
    int l = y >> 1, isc = y & 1;
    const float* src = h1;
    switch (y) { case 0: src = h1; break; case 1: src = c1; break;
                 case 2: src = h2; break; case 3: src = c2; break;
                 case 4: src = h3; break; case 5: src = c3; break;
                 case 6: src = h4; break; case 7: src = c4; break; }
    int g = blockIdx.x * 256 + threadIdx.x;  // float4 id, 16384 per array (grid.x 64)
    float4 v = ((const float4*)src)[g];
    if (isc) {
        ((float4*)(cbuf + l * (B_ * H_)))[g] = v;
    } else {
        union { uint2 u; _Float16 h[4]; } o;
        o.h[0] = (_Float16)v.x; o.h[1] = (_Float16)v.y;
        o.h[2] = (_Float16)v.z; o.h[3] = (_Float16)v.w;
        _Float16* dst = (l < 3) ? (h16 + (size_t)l * 2 * (B_ * H_)) : h4a;  // parity 0
        ((uint2*)dst)[g] = o.u;
    }
}

// ---------------- weight pre-swizzle: [KX][4096]W + [1024][4096]U -> frag stream -
// Fragment order: ((n*nsteps + s)*4 + gate) * 64 lanes * 8 halves.
// Lane l: kb=l>>4, cl=l&15 -> elem j reads k=s*32+kb*8+j, col=gate*1024+n*16+cl.
__global__ __launch_bounds__(256) void conv_wswz(const float* __restrict__ W,
                                                 const float* __restrict__ U,
                                                 int KX, int nsteps,
                                                 uint4* __restrict__ dst) {
    int s = blockIdx.x, n = blockIdx.y;
    int gate = threadIdx.x >> 6, lane = threadIdx.x & 63;
    int kb = lane >> 4, cl = lane & 15;
    int col = gate * H_ + n * 16 + cl;
    int k0 = s * 32 + kb * 8;
    union { uint4 u; _Float16 h[8]; } o;
    #pragma unroll
    for (int j = 0; j < 8; ++j) {
        int k = k0 + j;
        float v = (k < KX) ? W[(size_t)k * (4 * H_) + col]
                           : U[(size_t)(k - KX) * (4 * H_) + col];
        o.h[j] = (_Float16)v;
    }
    dst[((size_t)(n * nsteps + s) * 4 + gate) * 64 + lane] = o.u;
}

// ---------------- Wfc fp32 -> fp16 ----------------
__global__ __launch_bounds__(256) void conv_wfc16(const float* __restrict__ src,
                                                  _Float16* __restrict__ dst) {
    size_t g = (size_t)blockIdx.x * 256 + threadIdx.x;  // 8 elems each; grid 16000
    float4 a = ((const float4*)src)[g * 2];
    float4 b = ((const float4*)src)[g * 2 + 1];
    union { uint4 u; _Float16 h[8]; } o;
    o.h[0] = (_Float16)a.x; o.h[1] = (_Float16)a.y; o.h[2] = (_Float16)a.z; o.h[3] = (_Float16)a.w;
    o.h[4] = (_Float16)b.x; o.h[5] = (_Float16)b.y; o.h[6] = (_Float16)b.z; o.h[7] = (_Float16)b.w;
    ((uint4*)dst)[g] = o.u;
}

// ---------------- fused LSTM step: z = [x;h] @ Wswz, cell, h/c update ------------
// grid 64 (hcol tiles of 16), block 256 = 4 waves; wave w owns batch rows w*16..+15.
// No LDS, no barriers: B-frags stream from global (L1/L2-resident), A from h fp16.
template<int K0>
__global__ __launch_bounds__(256) void lstm_step(
    const _Float16* __restrict__ A0,   // [64][K0] x-part (emb slice or prev-layer h)
    const _Float16* __restrict__ A1,   // [64][1024] own h(t-1)
    const v8h* __restrict__ Wz,        // pre-swizzled frag stream
    const float* __restrict__ bias,    // [4096]
    float* __restrict__ cbuf,          // [64][1024] fp32, in-place
    _Float16* __restrict__ hout)       // [64][1024]
{
    constexpr int NSTEPS = (K0 + H_) / 32;
    constexpr int S0 = K0 / 32;
    const int tid = threadIdx.x;
    const int w = tid >> 6, l = tid & 63;
    const int q = l >> 4, ln = l & 15;
    const int arow = w * 16 + ln;
    const int bx = blockIdx.x;
    v4f acc0 = {0.f,0.f,0.f,0.f}, acc1 = {0.f,0.f,0.f,0.f};
    v4f acc2 = {0.f,0.f,0.f,0.f}, acc3 = {0.f,0.f,0.f,0.f};
    const v8h* wp = Wz + (size_t)bx * NSTEPS * 256 + l;
    const _Float16* a0p = A0 + (size_t)arow * K0 + q * 8;
    #pragma unroll 4
    for (int s = 0; s < S0; ++s) {
        v8h av = *(const v8h*)(a0p + s * 32);
        acc0 = __builtin_amdgcn_mfma_f32_16x16x32_f16(av, wp[0],   acc0, 0, 0, 0);
        acc1 = __builtin_amdgcn_mfma_f32_16x16x32_f16(av, wp[64],  acc1, 0, 0, 0);
        acc2 = __builtin_amdgcn_mfma_f32_16x16x32_f16(av, wp[128], acc2, 0, 0, 0);
        acc3 = __builtin_amdgcn_mfma_f32_16x16x32_f16(av, wp[192], acc3, 0, 0, 0);
        wp += 256;
    }
    const _Float16* a1p = A1 + (size_t)arow * H_ + q * 8;
    #pragma unroll 4
    for (int s = 0; s < NSTEPS - S0; ++s) {
        v8h av = *(const v8h*)(a1p + s * 32);
        acc0 = __builtin_amdgcn_mfma_f32_16x16x32_f16(av, wp[0],   acc0, 0, 0, 0);
        acc1 = __builtin_amdgcn_mfma_f32_16x16x32_f16(av, wp[64],  acc1, 0, 0, 0);
        acc2 = __builtin_amdgcn_mfma_f32_16x16x32_f16(av, wp[128], acc2, 0, 0, 0);
        acc3 = __builtin_amdgcn_mfma_f32_16x16x32_f16(av, wp[192], acc3, 0, 0, 0);
        wp += 256;
    }
    // epilogue: C/D layout col=ln, row=q*4+rr within wave's 16-row tile
    const int hcol = bx * 16 + ln;
    const float bi = bias[hcol], bf = bias[H_ + hcol];
    const float bg = bias[2 * H_ + hcol], bo = bias[3 * H_ + hcol];
    #pragma unroll
    for (int rr = 0; rr < 4; ++rr) {
        int row = w * 16 + q * 4 + rr;
        float zi = acc0[rr] + bi, zf = acc1[rr] + bf;
        float zg = acc2[rr] + bg, zo = acc3[rr] + bo;
        float c_old = cbuf[row * H_ + hcol];
        float si = 1.f / (1.f + __expf(-zi));
        float sf = 1.f / (1.f + __expf(-zf));
        float so = 1.f / (1.f + __expf(-zo));
        float tg = tanhf(zg);
        float cn = sf * c_old + si * tg;
        float hn = so * tanhf(cn);
        cbuf[row * H_ + hcol] = cn;
        hout[row * H_ + hcol] = (_Float16)hn;
    }
}

// ---------------- FC GEMM: logits = h4a(fp16) @ Wfc(fp16) + bfc -> d_out ---------
// A rows ra = t*64+b; output row ro = b*64+t. Tile 64(M) x 128(N), BK=32.
__global__ __launch_bounds__(256) void fc_gemm(const unsigned short* __restrict__ A,
                                               const unsigned short* __restrict__ Bw,
                                               const float* __restrict__ bfc,
                                               float* __restrict__ out) {
    __shared__ unsigned short As[64][40];   // +8 pad -> 80B rows (16B-multiple): free
    __shared__ unsigned short Bs[128][40];  // stored transposed: Bs[n][k]
    const int tid = threadIdx.x;
    const int w = tid >> 6, l = tid & 63;
    const int q = l >> 4, ln = l & 15;
    const int mBlock = blockIdx.y * 64;
    const int nBlock = blockIdx.x * 128;
    v4f acc[8];
    #pragma unroll
    for (int j = 0; j < 8; ++j) acc[j] = (v4f){0.f, 0.f, 0.f, 0.f};
    const int ai = tid >> 2, au = tid & 3;
    for (int k0 = 0; k0 < H_; k0 += 32) {
        uint4 av = ((const uint4*)A)[(size_t)(mBlock + ai) * (H_ / 8) + (k0 >> 3) + au];
        int e0 = tid, e1 = tid + 256;
        int kk0 = e0 >> 4, nj0 = e0 & 15;
        int kk1 = e1 >> 4, nj1 = e1 & 15;
        union { uint4 v; unsigned short s[8]; } b0, b1;
        b0.v = ((const uint4*)Bw)[(size_t)(k0 + kk0) * (V_ / 8) + (nBlock >> 3) + nj0];
        b1.v = ((const uint4*)Bw)[(size_t)(k0 + kk1) * (V_ / 8) + (nBlock >> 3) + nj1];
        __syncthreads();   // prior iteration's frag reads done
        *(uint4*)&As[ai][au * 8] = av;
        #pragma unroll
        for (int s = 0; s < 8; ++s) Bs[nj0 * 8 + s][kk0] = b0.s[s];
        #pragma unroll
        for (int s = 0; s < 8; ++s) Bs[nj1 * 8 + s][kk1] = b1.s[s];
        __syncthreads();
        v8h afr = *(const v8h*)&As[w * 16 + ln][q * 8];
        #pragma unroll
        for (int j = 0; j < 8; ++j) {
            v8h bfr = *(const v8h*)&Bs[j * 16 + ln][q * 8];
            acc[j] = __builtin_amdgcn_mfma_f32_16x16x32_f16(afr, bfr, acc[j], 0, 0, 0);
        }
    }
    #pragma unroll
    for (int j = 0; j < 8; ++j) {
        int n = nBlock + j * 16 + ln;
        float bias = bfc[n];
        #pragma unroll
        for (int rr = 0; rr < 4; ++rr) {
            int ra = mBlock + w * 16 + q * 4 + rr;           // t*64+b
            int ro = ((ra & 63) << 6) | (ra >> 6);           // b*64+t
            out[(size_t)ro * V_ + n] = acc[j][rr] + bias;
        }
    }
}

// ---------------- softmax: stats then normalize (in-place on d_out) --------------
__global__ __launch_bounds__(256) void softmax_stats(const float* __restrict__ out,
                                                     float* __restrict__ stats) {
    __shared__ float red[256];
    int ro = blockIdx.x;
    const float* row = out + (size_t)ro * V_;
    int tid = threadIdx.x;
    float m = -3.4e38f;
    for (int i = tid; i < V_; i += 256) m = fmaxf(m, row[i]);
    red[tid] = m; __syncthreads();
    for (int s = 128; s; s >>= 1) {
        if (tid < s) red[tid] = fmaxf(red[tid], red[tid + s]);
        __syncthreads();
    }
    float M = red[0];
    __syncthreads();
    float l = 0.f;
    for (int i = tid; i < V_; i += 256) l += __expf(row[i] - M);
    red[tid] = l; __syncthreads();
    for (int s = 128; s; s >>= 1) {
        if (tid < s) red[tid] += red[tid + s];
        __syncthreads();
    }
    if (tid == 0) { stats[ro * 2] = M; stats[ro * 2 + 1] = 1.f / red[0]; }
}

__global__ __launch_bounds__(256) void softmax_norm(float* __restrict__ out,
                                                    const float* __restrict__ stats) {
    int ro = blockIdx.y;
    int slot = blockIdx.x * 256 + threadIdx.x;  // grid.x = 32 -> 8192 slots, 8000 used
    if (slot >= V_ / 4) return;
    float M = stats[ro * 2], inv = stats[ro * 2 + 1];
    float4* p = (float4*)(out + (size_t)ro * V_);
    float4 v = p[slot];
    v.x = __expf(v.x - M) * inv;
    v.y = __expf(v.y - M) * inv;
    v.z = __expf(v.z - M) * inv;
    v.w = __expf(v.w - M) * inv;
    p[slot] = v;
}

extern "C" void kernel_launch(void* const* d_in, const int* in_sizes, int n_in,
                              void* d_out, int out_size, void* d_ws, size_t ws_size,
                              hipStream_t stream) {
    const int* idx = (const int*)d_in[0];
    const float* h0[4] = {(const float*)d_in[1], (const float*)d_in[3],
                          (const float*)d_in[5], (const float*)d_in[7]};
    const float* c0[4] = {(const float*)d_in[2], (const float*)d_in[4],
                          (const float*)d_in[6], (const float*)d_in[8]};
    const float* emb = (const float*)d_in[9];
    const float* W[4], *U[4], *bb[4];
    for (int l = 0; l < 4; ++l) {
        W[l]  = (const float*)d_in[10 + 3 * l];
        U[l]  = (const float*)d_in[11 + 3 * l];
        bb[l] = (const float*)d_in[12 + 3 * l];
    }
    const float* Wfc = (const float*)d_in[22];
    const float* bfc = (const float*)d_in[23];
    float* out = (float*)d_out;

    // ws layout (bytes):
    //   X16   @ 0         4,194,304   [T][B][E] fp16
    //   h16   @ 4194304     786,432   [3 layers][2 parity][64][1024] fp16
    //   cbuf  @ 4980736   1,048,576   [4][64][1024] fp32
    //   h4a   @ 6029312   8,519,680   [T+1][64][1024] fp16 (slot 0 = init)
    //   stats @ 14548992     32,768   [4096][2] fp32
    //   Wz    @ 16777216 62,914,560   pre-swizzled fp16 W|U frags (4 layers)
    //   wfc16 @ 16777216 65,536,000   ALIAS of Wz: converted after recurrence done
    char* ws = (char*)d_ws;
    _Float16* X16   = (_Float16*)ws;
    _Float16* h16   = (_Float16*)(ws + 4194304);
    float*    cbuf  = (float*)(ws + 4980736);
    _Float16* h4a   = (_Float16*)(ws + 6029312);
    float*    stats = (float*)(ws + 14548992);
    uint4*    Wz    = (uint4*)(ws + 16777216);
    _Float16* wfc16 = (_Float16*)(ws + 16777216);

    // Wz per-layer bases (uint4 units): l0 has 48 k-steps, l1..3 have 64.
    uint4* Wz0 = Wz;
    uint4* Wz1 = Wz0 + (size_t)64 * 48 * 4 * 64;   // 786432
    uint4* Wz2 = Wz1 + (size_t)64 * 64 * 4 * 64;   // +1048576
    uint4* Wz3 = Wz2 + (size_t)64 * 64 * 4 * 64;

    gather_embed16<<<1024, 256, 0, stream>>>(idx, emb, X16);
    init_state16<<<dim3(64, 8), 256, 0, stream>>>(h0[0], c0[0], h0[1], c0[1],
                                                  h0[2], c0[2], h0[3], c0[3],
                                                  h16, h4a, cbuf);
    conv_wswz<<<dim3(48, 64), 256, 0, stream>>>(W[0], U[0], E_, 48, Wz0);
    conv_wswz<<<dim3(64, 64), 256, 0, stream>>>(W[1], U[1], H_, 64, Wz1);
    conv_wswz<<<dim3(64, 64), 256, 0, stream>>>(W[2], U[2], H_, 64, Wz2);
    conv_wswz<<<dim3(64, 64), 256, 0, stream>>>(W[3], U[3], H_, 64, Wz3);

    const int SL = B_ * H_;  // 65536 halves / floats per state slot
    for (int t = 0; t < T_; ++t) {
        int p = t & 1, qq = p ^ 1;  // read parity p, write parity qq
        lstm_step<512><<<64, 256, 0, stream>>>(
            X16 + (size_t)t * (B_ * E_), h16 + (0 * 2 + p) * SL, (const v8h*)Wz0,
            bb[0], cbuf + 0 * SL, h16 + (0 * 2 + qq) * SL);
        lstm_step<1024><<<64, 256, 0, stream>>>(
            h16 + (0 * 2 + qq) * SL, h16 + (1 * 2 + p) * SL, (const v8h*)Wz1,
            bb[1], cbuf + 1 * SL, h16 + (1 * 2 + qq) * SL);
        lstm_step<1024><<<64, 256, 0, stream>>>(
            h16 + (1 * 2 + qq) * SL, h16 + (2 * 2 + p) * SL, (const v8h*)Wz2,
            bb[2], cbuf + 2 * SL, h16 + (2 * 2 + qq) * SL);
        lstm_step<1024><<<64, 256, 0, stream>>>(
            h16 + (2 * 2 + qq) * SL, h4a + (size_t)t * SL, (const v8h*)Wz3,
            bb[3], cbuf + 3 * SL, h4a + (size_t)(t + 1) * SL);
    }

    // Wfc conversion AFTER the recurrence (wfc16 aliases Wz; stream order protects it)
    conv_wfc16<<<16000, 256, 0, stream>>>(Wfc, wfc16);
    fc_gemm<<<dim3(V_ / 128, (T_ * B_) / 64), 256, 0, stream>>>(
        (const unsigned short*)(h4a + SL), (const unsigned short*)wfc16, bfc, out);
    softmax_stats<<<T_ * B_, 256, 0, stream>>>(out, stats);
    softmax_norm<<<dim3(32, T_ * B_), 256, 0, stream>>>(out, stats);
}